// Round 1
// baseline (1018.726 us; speedup 1.0000x reference)
//
#include <hip/hip_runtime.h>
#include <hip/hip_bf16.h>
#include <math.h>

#define N_NODES 50000
#define F_IN 128
#define HID 64
#define NCLS 40
#define K_STACKS 2

// ---------------- CSR build ----------------

__global__ void deg_hist_kernel(const int* __restrict__ dst, int* __restrict__ deg, int E) {
    int e = blockIdx.x * blockDim.x + threadIdx.x;
    if (e < E) atomicAdd(&deg[dst[e]], 1);
}

__global__ void dinv_kernel(const int* __restrict__ deg, float* __restrict__ dinv, int n) {
    int i = blockIdx.x * blockDim.x + threadIdx.x;
    if (i < n) {
        int d = deg[i];
        dinv[i] = (d > 0) ? (1.0f / sqrtf((float)d)) : 0.0f;
    }
}

// one block of 1024 threads; exclusive scan of deg -> row_ptr[0..n]
__global__ void scan_kernel(const int* __restrict__ deg, int* __restrict__ row_ptr, int n) {
    __shared__ int lds[1024];
    int tid = threadIdx.x;
    int chunk = (n + 1023) / 1024;
    int start = tid * chunk;
    int end = min(start + chunk, n);
    int s = 0;
    for (int i = start; i < end; ++i) s += deg[i];
    lds[tid] = s;
    __syncthreads();
    // Hillis-Steele inclusive scan over 1024 partials
    for (int off = 1; off < 1024; off <<= 1) {
        int v = lds[tid];
        int add = (tid >= off) ? lds[tid - off] : 0;
        __syncthreads();
        lds[tid] = v + add;
        __syncthreads();
    }
    int excl = (tid == 0) ? 0 : lds[tid - 1];
    if (tid == 0) row_ptr[0] = 0;
    int run = excl;
    for (int i = start; i < end; ++i) {
        run += deg[i];
        row_ptr[i + 1] = run;
    }
}

__global__ void scatter_kernel(const int* __restrict__ src, const int* __restrict__ dst,
                               const int* __restrict__ row_ptr, int* __restrict__ cursor,
                               const float* __restrict__ dinv,
                               int* __restrict__ col, float* __restrict__ ew, int E) {
    int e = blockIdx.x * blockDim.x + threadIdx.x;
    if (e < E) {
        int s = src[e], d = dst[e];
        int ofs = atomicAdd(&cursor[d], 1);
        int pos = row_ptr[d] + ofs;
        col[pos] = s;
        ew[pos] = dinv[s] * dinv[d];
    }
}

// ---------------- Dense GEMM (fp32 vector ALU) ----------------
// out[k][n][f] = sum_c A[(k)][n][c] * W[k][c][f]
// block: 256 threads computes 64 nodes x COUT(<=64) feats for one k.
template <int CIN>
__global__ __launch_bounds__(256) void gemm_kernel(
    const float* __restrict__ A, const float* __restrict__ W,
    float* __restrict__ out, int N, int COUT, int a_per_k) {
    __shared__ float xT[CIN][64];     // A tile, transposed: [c][node]
    __shared__ float Wt[CIN * 64];    // weight slice [c][f], f contiguous

    const int k = blockIdx.y;
    const int n0 = blockIdx.x * 64;
    const int t = threadIdx.x;
    const float* Ab = A + (a_per_k ? (size_t)k * N * CIN : (size_t)0);

    // stage A tile (transposed) — float4 global loads, scalar LDS writes (2-way bank = free)
    {
        int nl = t & 63;
        int n = n0 + nl;
        const float* row = Ab + (size_t)n * CIN;
        for (int c0 = (t >> 6) * 4; c0 < CIN; c0 += 16) {
            float4 v = make_float4(0.f, 0.f, 0.f, 0.f);
            if (n < N) v = *(const float4*)(row + c0);
            xT[c0 + 0][nl] = v.x;
            xT[c0 + 1][nl] = v.y;
            xT[c0 + 2][nl] = v.z;
            xT[c0 + 3][nl] = v.w;
        }
    }
    // stage W slice
    {
        const float* Wk = W + (size_t)k * CIN * COUT;
        int total = CIN * COUT;
        for (int i = t * 4; i < total; i += 1024) {
            *(float4*)(&Wt[i]) = *(const float4*)(Wk + i);
        }
    }
    __syncthreads();

    const int tx = t & 15;   // feat group: feats tx*4..tx*4+3
    const int ty = t >> 4;   // node group: nodes ty*4..ty*4+3
    if (tx * 4 < COUT) {
        float acc[4][4] = {};
#pragma unroll 4
        for (int c = 0; c < CIN; ++c) {
            const float4 av = *(const float4*)(&xT[c][ty * 4]);
            const float4 wv = *(const float4*)(&Wt[c * COUT + tx * 4]);
            const float aa[4] = {av.x, av.y, av.z, av.w};
            const float ww[4] = {wv.x, wv.y, wv.z, wv.w};
#pragma unroll
            for (int i = 0; i < 4; ++i)
#pragma unroll
                for (int j = 0; j < 4; ++j) acc[i][j] += aa[i] * ww[j];
        }
#pragma unroll
        for (int i = 0; i < 4; ++i) {
            int n = n0 + ty * 4 + i;
            if (n < N) {
                float4 v = make_float4(acc[i][0], acc[i][1], acc[i][2], acc[i][3]);
                *(float4*)(out + ((size_t)k * N + n) * COUT + tx * 4) = v;
            }
        }
    }
}

// ---------------- Sparse aggregation (CSR gather) + fused epilogue ----------------
// out[k][n][f] = act( sum_{e in row n} ew[e]*h[k][col[e]][f] + root[k][n][f] + bias[k][f] )
template <int F>
__global__ __launch_bounds__(256) void agg_kernel(
    const float* __restrict__ h, const int* __restrict__ row_ptr,
    const int* __restrict__ col, const float* __restrict__ ew,
    const float* __restrict__ root, const float* __restrict__ bias,
    float* __restrict__ out, int N, int do_relu) {
    int wid = (blockIdx.x * blockDim.x + threadIdx.x) >> 6;  // wave id
    int lane = threadIdx.x & 63;
    int node = wid >> 1;
    int k = wid & 1;
    if (node >= N) return;
    if (lane >= F) return;
    int e0 = row_ptr[node];
    int e1 = row_ptr[node + 1];
    const float* hk = h + (size_t)k * N * F;
    float acc = 0.f;
    for (int e = e0; e < e1; ++e) {
        int s = col[e];
        acc += ew[e] * hk[(size_t)s * F + lane];
    }
    size_t o = ((size_t)k * N + node) * F + lane;
    float val = acc + root[o] + bias[k * F + lane];
    if (do_relu) val = fmaxf(val, 0.f);
    out[o] = val;
}

// h1 = relu(mean over k)  (relu is a no-op here but matches the wrapper)
__global__ void mean_relu_kernel(const float* __restrict__ in, float* __restrict__ out,
                                 size_t cnt, size_t stride) {
    size_t i = (size_t)blockIdx.x * blockDim.x + threadIdx.x;
    if (i < cnt) out[i] = fmaxf(0.5f * (in[i] + in[i + stride]), 0.f);
}

// out = log_softmax(mean over k of g), rows of NCLS=40; one wave per node
__global__ __launch_bounds__(256) void lsm_kernel(const float* __restrict__ g,
                                                  float* __restrict__ out, int N) {
    int wid = (blockIdx.x * blockDim.x + threadIdx.x) >> 6;
    int lane = threadIdx.x & 63;
    if (wid >= N) return;
    float v = -INFINITY;
    if (lane < NCLS)
        v = 0.5f * (g[(size_t)wid * NCLS + lane] + g[((size_t)N + wid) * NCLS + lane]);
    float m = v;
#pragma unroll
    for (int off = 32; off; off >>= 1) m = fmaxf(m, __shfl_xor(m, off));
    float ex = (lane < NCLS) ? expf(v - m) : 0.f;
    float s = ex;
#pragma unroll
    for (int off = 32; off; off >>= 1) s += __shfl_xor(s, off);
    float r = v - m - logf(s);
    if (lane < NCLS) out[(size_t)wid * NCLS + lane] = r;
}

// ---------------- launch ----------------

static inline size_t align256(size_t x) { return (x + 255) & ~(size_t)255; }

extern "C" void kernel_launch(void* const* d_in, const int* in_sizes, int n_in,
                              void* d_out, int out_size, void* d_ws, size_t ws_size,
                              hipStream_t stream) {
    const float* x = (const float*)d_in[0];
    const int* ei = (const int*)d_in[1];
    const float* w1_init = (const float*)d_in[2];
    const float* w1 = (const float*)d_in[3];
    const float* v1 = (const float*)d_in[4];
    const float* b1 = (const float*)d_in[5];
    const float* w2_init = (const float*)d_in[6];
    const float* w2 = (const float*)d_in[7];
    const float* v2 = (const float*)d_in[8];
    const float* b2 = (const float*)d_in[9];

    const int N = in_sizes[0] / F_IN;
    const int E = in_sizes[1] / 2;
    const int* src = ei;
    const int* dst = ei + E;

    // workspace carve
    char* p = (char*)d_ws;
    auto take = [&](size_t bytes) {
        char* r = p;
        p += align256(bytes);
        return r;
    };
    int* deg = (int*)take((size_t)N * 4);
    int* cursor = (int*)take((size_t)N * 4);
    float* dinv = (float*)take((size_t)N * 4);
    int* row_ptr = (int*)take((size_t)(N + 1) * 4);
    int* col = (int*)take((size_t)E * 4);
    float* ew = (float*)take((size_t)E * 4);
    float* bufA = (float*)take((size_t)K_STACKS * N * HID * 4);  // root
    float* bufB = (float*)take((size_t)K_STACKS * N * HID * 4);  // h
    float* bufC = (float*)take((size_t)K_STACKS * N * HID * 4);  // agg/out
    float* h1 = (float*)take((size_t)N * HID * 4);

    hipMemsetAsync(deg, 0, (size_t)N * 4, stream);
    hipMemsetAsync(cursor, 0, (size_t)N * 4, stream);

    const int TB = 256;
    deg_hist_kernel<<<(E + TB - 1) / TB, TB, 0, stream>>>(dst, deg, E);
    dinv_kernel<<<(N + TB - 1) / TB, TB, 0, stream>>>(deg, dinv, N);
    scan_kernel<<<1, 1024, 0, stream>>>(deg, row_ptr, N);
    scatter_kernel<<<(E + TB - 1) / TB, TB, 0, stream>>>(src, dst, row_ptr, cursor, dinv, col, ew, E);

    dim3 ggrid((N + 63) / 64, K_STACKS);
    const int agg_blocks = (N * K_STACKS + 3) / 4;  // 4 waves/block, 1 wave per (node,k)

    // ----- layer 1: F_IN=128 -> HID=64, act=relu -----
    gemm_kernel<F_IN><<<ggrid, 256, 0, stream>>>(x, v1, bufA, N, HID, 0);       // root1
    gemm_kernel<F_IN><<<ggrid, 256, 0, stream>>>(x, w1_init, bufB, N, HID, 0);  // h (t=0)
    agg_kernel<HID><<<agg_blocks, 256, 0, stream>>>(bufB, row_ptr, col, ew, bufA, b1, bufC, N, 1);
    gemm_kernel<HID><<<ggrid, 256, 0, stream>>>(bufC, w1, bufB, N, HID, 1);     // h (t=1)
    agg_kernel<HID><<<agg_blocks, 256, 0, stream>>>(bufB, row_ptr, col, ew, bufA, b1, bufC, N, 1);
    {
        size_t cnt = (size_t)N * HID;
        mean_relu_kernel<<<(cnt + TB - 1) / TB, TB, 0, stream>>>(bufC, h1, cnt, cnt);
    }

    // ----- layer 2: HID=64 -> NCLS=40, act=identity -----
    gemm_kernel<HID><<<ggrid, 256, 0, stream>>>(h1, v2, bufA, N, NCLS, 0);       // root2
    gemm_kernel<HID><<<ggrid, 256, 0, stream>>>(h1, w2_init, bufB, N, NCLS, 0);  // g (t=0)
    agg_kernel<NCLS><<<agg_blocks, 256, 0, stream>>>(bufB, row_ptr, col, ew, bufA, b2, bufC, N, 0);
    gemm_kernel<NCLS><<<ggrid, 256, 0, stream>>>(bufC, w2, bufB, N, NCLS, 1);    // g (t=1)
    agg_kernel<NCLS><<<agg_blocks, 256, 0, stream>>>(bufB, row_ptr, col, ew, bufA, b2, bufC, N, 0);

    lsm_kernel<<<(N + 3) / 4, 256, 0, stream>>>(bufC, (float*)d_out, N);
}

// Round 2
// 644.868 us; speedup vs baseline: 1.5797x; 1.5797x over previous
//
#include <hip/hip_runtime.h>
#include <hip/hip_bf16.h>
#include <math.h>

#define N_NODES 50000
#define F_IN 128
#define HID 64
#define NCLS 40
#define K_STACKS 2

// ---------------- CSR build ----------------

__global__ void deg_hist_kernel(const int* __restrict__ dst, int* __restrict__ deg, int E) {
    int e = blockIdx.x * blockDim.x + threadIdx.x;
    if (e < E) atomicAdd(&deg[dst[e]], 1);
}

__global__ void dinv_kernel(const int* __restrict__ deg, float* __restrict__ dinv, int n) {
    int i = blockIdx.x * blockDim.x + threadIdx.x;
    if (i < n) {
        int d = deg[i];
        dinv[i] = (d > 0) ? (1.0f / sqrtf((float)d)) : 0.0f;
    }
}

// one block of 1024 threads; exclusive scan of deg -> row_ptr[0..n]
__global__ void scan_kernel(const int* __restrict__ deg, int* __restrict__ row_ptr, int n) {
    __shared__ int lds[1024];
    int tid = threadIdx.x;
    int chunk = (n + 1023) / 1024;
    int start = tid * chunk;
    int end = min(start + chunk, n);
    int s = 0;
    for (int i = start; i < end; ++i) s += deg[i];
    lds[tid] = s;
    __syncthreads();
    for (int off = 1; off < 1024; off <<= 1) {
        int v = lds[tid];
        int add = (tid >= off) ? lds[tid - off] : 0;
        __syncthreads();
        lds[tid] = v + add;
        __syncthreads();
    }
    int excl = (tid == 0) ? 0 : lds[tid - 1];
    if (tid == 0) row_ptr[0] = 0;
    int run = excl;
    for (int i = start; i < end; ++i) {
        run += deg[i];
        row_ptr[i + 1] = run;
    }
}

__global__ void scatter_kernel(const int* __restrict__ src, const int* __restrict__ dst,
                               const int* __restrict__ row_ptr, int* __restrict__ cursor,
                               const float* __restrict__ dinv,
                               int* __restrict__ col, float* __restrict__ ew, int E) {
    int e = blockIdx.x * blockDim.x + threadIdx.x;
    if (e < E) {
        int s = src[e], d = dst[e];
        int ofs = atomicAdd(&cursor[d], 1);
        int pos = row_ptr[d] + ofs;
        col[pos] = s;
        ew[pos] = dinv[s] * dinv[d];
    }
}

// ---------------- Dense GEMM (fp32 vector ALU) ----------------
template <int CIN>
__global__ __launch_bounds__(256) void gemm_kernel(
    const float* __restrict__ A, const float* __restrict__ W,
    float* __restrict__ out, int N, int COUT, int a_per_k) {
    __shared__ float xT[CIN][64];
    __shared__ float Wt[CIN * 64];

    const int k = blockIdx.y;
    const int n0 = blockIdx.x * 64;
    const int t = threadIdx.x;
    const float* Ab = A + (a_per_k ? (size_t)k * N * CIN : (size_t)0);

    {
        int nl = t & 63;
        int n = n0 + nl;
        const float* row = Ab + (size_t)n * CIN;
        for (int c0 = (t >> 6) * 4; c0 < CIN; c0 += 16) {
            float4 v = make_float4(0.f, 0.f, 0.f, 0.f);
            if (n < N) v = *(const float4*)(row + c0);
            xT[c0 + 0][nl] = v.x;
            xT[c0 + 1][nl] = v.y;
            xT[c0 + 2][nl] = v.z;
            xT[c0 + 3][nl] = v.w;
        }
    }
    {
        const float* Wk = W + (size_t)k * CIN * COUT;
        int total = CIN * COUT;
        for (int i = t * 4; i < total; i += 1024) {
            *(float4*)(&Wt[i]) = *(const float4*)(Wk + i);
        }
    }
    __syncthreads();

    const int tx = t & 15;
    const int ty = t >> 4;
    if (tx * 4 < COUT) {
        float acc[4][4] = {};
#pragma unroll 4
        for (int c = 0; c < CIN; ++c) {
            const float4 av = *(const float4*)(&xT[c][ty * 4]);
            const float4 wv = *(const float4*)(&Wt[c * COUT + tx * 4]);
            const float aa[4] = {av.x, av.y, av.z, av.w};
            const float ww[4] = {wv.x, wv.y, wv.z, wv.w};
#pragma unroll
            for (int i = 0; i < 4; ++i)
#pragma unroll
                for (int j = 0; j < 4; ++j) acc[i][j] += aa[i] * ww[j];
        }
#pragma unroll
        for (int i = 0; i < 4; ++i) {
            int n = n0 + ty * 4 + i;
            if (n < N) {
                float4 v = make_float4(acc[i][0], acc[i][1], acc[i][2], acc[i][3]);
                *(float4*)(out + ((size_t)k * N + n) * COUT + tx * 4) = v;
            }
        }
    }
}

// ---------------- Sparse aggregation v2: float4 gathers, 16-edge chunks ----------------
// One wave per (node,k). lane = (sub = lane>>4 edge slot, fq = lane&15 feature quad).
// Per 16-edge chunk: 4 independent float4 gathers in flight (4 KB/wave), masked
// tail edges redirected to row 0 with weight 0 (branchless, address always valid).
template <int F>
__global__ __launch_bounds__(256) void agg_kernel(
    const float* __restrict__ h, const int* __restrict__ row_ptr,
    const int* __restrict__ col, const float* __restrict__ ew,
    const float* __restrict__ root, const float* __restrict__ bias,
    float* __restrict__ out, int N, int do_relu) {
    constexpr int FQ = F / 4;  // feature quads per row (16 for F=64, 10 for F=40)
    int wid = (blockIdx.x * blockDim.x + threadIdx.x) >> 6;
    int lane = threadIdx.x & 63;
    int node = wid >> 1;
    int k = wid & 1;
    if (node >= N) return;
    int e0 = row_ptr[node];
    int deg = row_ptr[node + 1] - e0;
    const float* hk = h + (size_t)k * N * F;
    const int sub = lane >> 4;
    const int fq = lane & 15;
    const int fqc = (fq < FQ) ? fq : 0;  // clamp inactive lanes to a valid quad

    float4 acc = make_float4(0.f, 0.f, 0.f, 0.f);
    for (int w0 = 0; w0 < deg; w0 += 64) {
        // coalesced preload of up to 64 edges' col/ew for this wave
        int mye = w0 + lane;
        int c = 0;
        float wt = 0.f;
        if (mye < deg) {
            c = col[e0 + mye];
            wt = ew[e0 + mye];
        }
        int nch = min(deg - w0, 64);
        for (int base = 0; base < nch; base += 16) {
            float4 v[4];
            float wj[4];
#pragma unroll
            for (int u = 0; u < 4; ++u) {
                int j = base + u * 4 + sub;
                int cj = __shfl(c, j);
                float wv = __shfl(wt, j);
                bool ok = (j < nch);
                wj[u] = ok ? wv : 0.f;
                int cs = ok ? cj : 0;
                v[u] = *(const float4*)(hk + (size_t)cs * F + fqc * 4);
            }
#pragma unroll
            for (int u = 0; u < 4; ++u) {
                acc.x += wj[u] * v[u].x;
                acc.y += wj[u] * v[u].y;
                acc.z += wj[u] * v[u].z;
                acc.w += wj[u] * v[u].w;
            }
        }
    }
    // reduce across the 4 edge slots (lanes differing in bits 4..5)
#pragma unroll
    for (int m = 16; m < 64; m <<= 1) {
        acc.x += __shfl_xor(acc.x, m);
        acc.y += __shfl_xor(acc.y, m);
        acc.z += __shfl_xor(acc.z, m);
        acc.w += __shfl_xor(acc.w, m);
    }
    if (sub == 0 && fq < FQ) {
        size_t o = ((size_t)k * N + node) * F + fq * 4;
        float4 r = *(const float4*)(root + o);
        float4 b = *(const float4*)(bias + (size_t)k * F + fq * 4);
        float4 val = make_float4(acc.x + r.x + b.x, acc.y + r.y + b.y,
                                 acc.z + r.z + b.z, acc.w + r.w + b.w);
        if (do_relu) {
            val.x = fmaxf(val.x, 0.f);
            val.y = fmaxf(val.y, 0.f);
            val.z = fmaxf(val.z, 0.f);
            val.w = fmaxf(val.w, 0.f);
        }
        *(float4*)(out + o) = val;
    }
}

// h1 = relu(mean over k)
__global__ void mean_relu_kernel(const float* __restrict__ in, float* __restrict__ out,
                                 size_t cnt, size_t stride) {
    size_t i = (size_t)blockIdx.x * blockDim.x + threadIdx.x;
    if (i < cnt) out[i] = fmaxf(0.5f * (in[i] + in[i + stride]), 0.f);
}

// out = log_softmax(mean over k of g); one wave per node
__global__ __launch_bounds__(256) void lsm_kernel(const float* __restrict__ g,
                                                  float* __restrict__ out, int N) {
    int wid = (blockIdx.x * blockDim.x + threadIdx.x) >> 6;
    int lane = threadIdx.x & 63;
    if (wid >= N) return;
    float v = -INFINITY;
    if (lane < NCLS)
        v = 0.5f * (g[(size_t)wid * NCLS + lane] + g[((size_t)N + wid) * NCLS + lane]);
    float m = v;
#pragma unroll
    for (int off = 32; off; off >>= 1) m = fmaxf(m, __shfl_xor(m, off));
    float ex = (lane < NCLS) ? expf(v - m) : 0.f;
    float s = ex;
#pragma unroll
    for (int off = 32; off; off >>= 1) s += __shfl_xor(s, off);
    float r = v - m - logf(s);
    if (lane < NCLS) out[(size_t)wid * NCLS + lane] = r;
}

// ---------------- launch ----------------

static inline size_t align256(size_t x) { return (x + 255) & ~(size_t)255; }

extern "C" void kernel_launch(void* const* d_in, const int* in_sizes, int n_in,
                              void* d_out, int out_size, void* d_ws, size_t ws_size,
                              hipStream_t stream) {
    const float* x = (const float*)d_in[0];
    const int* ei = (const int*)d_in[1];
    const float* w1_init = (const float*)d_in[2];
    const float* w1 = (const float*)d_in[3];
    const float* v1 = (const float*)d_in[4];
    const float* b1 = (const float*)d_in[5];
    const float* w2_init = (const float*)d_in[6];
    const float* w2 = (const float*)d_in[7];
    const float* v2 = (const float*)d_in[8];
    const float* b2 = (const float*)d_in[9];

    const int N = in_sizes[0] / F_IN;
    const int E = in_sizes[1] / 2;
    const int* src = ei;
    const int* dst = ei + E;

    char* p = (char*)d_ws;
    auto take = [&](size_t bytes) {
        char* r = p;
        p += align256(bytes);
        return r;
    };
    int* deg = (int*)take((size_t)N * 4);
    int* cursor = (int*)take((size_t)N * 4);
    float* dinv = (float*)take((size_t)N * 4);
    int* row_ptr = (int*)take((size_t)(N + 1) * 4);
    int* col = (int*)take((size_t)E * 4);
    float* ew = (float*)take((size_t)E * 4);
    float* bufA = (float*)take((size_t)K_STACKS * N * HID * 4);  // root
    float* bufB = (float*)take((size_t)K_STACKS * N * HID * 4);  // h
    float* bufC = (float*)take((size_t)K_STACKS * N * HID * 4);  // agg/out
    float* h1 = (float*)take((size_t)N * HID * 4);

    hipMemsetAsync(deg, 0, (size_t)N * 4, stream);
    hipMemsetAsync(cursor, 0, (size_t)N * 4, stream);

    const int TB = 256;
    deg_hist_kernel<<<(E + TB - 1) / TB, TB, 0, stream>>>(dst, deg, E);
    dinv_kernel<<<(N + TB - 1) / TB, TB, 0, stream>>>(deg, dinv, N);
    scan_kernel<<<1, 1024, 0, stream>>>(deg, row_ptr, N);
    scatter_kernel<<<(E + TB - 1) / TB, TB, 0, stream>>>(src, dst, row_ptr, cursor, dinv, col, ew, E);

    dim3 ggrid((N + 63) / 64, K_STACKS);
    const int agg_blocks = (N * K_STACKS + 3) / 4;  // 4 waves/block, 1 wave per (node,k)

    // ----- layer 1: F_IN=128 -> HID=64, act=relu -----
    gemm_kernel<F_IN><<<ggrid, 256, 0, stream>>>(x, v1, bufA, N, HID, 0);       // root1
    gemm_kernel<F_IN><<<ggrid, 256, 0, stream>>>(x, w1_init, bufB, N, HID, 0);  // h (t=0)
    agg_kernel<HID><<<agg_blocks, 256, 0, stream>>>(bufB, row_ptr, col, ew, bufA, b1, bufC, N, 1);
    gemm_kernel<HID><<<ggrid, 256, 0, stream>>>(bufC, w1, bufB, N, HID, 1);     // h (t=1)
    agg_kernel<HID><<<agg_blocks, 256, 0, stream>>>(bufB, row_ptr, col, ew, bufA, b1, bufC, N, 1);
    {
        size_t cnt = (size_t)N * HID;
        mean_relu_kernel<<<(cnt + TB - 1) / TB, TB, 0, stream>>>(bufC, h1, cnt, cnt);
    }

    // ----- layer 2: HID=64 -> NCLS=40, act=identity -----
    gemm_kernel<HID><<<ggrid, 256, 0, stream>>>(h1, v2, bufA, N, NCLS, 0);       // root2
    gemm_kernel<HID><<<ggrid, 256, 0, stream>>>(h1, w2_init, bufB, N, NCLS, 0);  // g (t=0)
    agg_kernel<NCLS><<<agg_blocks, 256, 0, stream>>>(bufB, row_ptr, col, ew, bufA, b2, bufC, N, 0);
    gemm_kernel<NCLS><<<ggrid, 256, 0, stream>>>(bufC, w2, bufB, N, NCLS, 1);    // g (t=1)
    agg_kernel<NCLS><<<agg_blocks, 256, 0, stream>>>(bufB, row_ptr, col, ew, bufA, b2, bufC, N, 0);

    lsm_kernel<<<(N + 3) / 4, 256, 0, stream>>>(bufC, (float*)d_out, N);
}

// Round 3
// 583.371 us; speedup vs baseline: 1.7463x; 1.1054x over previous
//
#include <hip/hip_runtime.h>
#include <hip/hip_bf16.h>
#include <math.h>

#define N_NODES 50000
#define F_IN 128
#define HID 64
#define NCLS 40
#define K_STACKS 2
#define SCAN_TILE 1024  // elements per scan block (256 threads x 4)

// ---------------- CSR build ----------------

__global__ void deg_hist_kernel(const int* __restrict__ dst, int* __restrict__ deg, int E) {
    int e = blockIdx.x * blockDim.x + threadIdx.x;
    if (e < E) atomicAdd(&deg[dst[e]], 1);
}

__global__ void dinv_kernel(const int* __restrict__ deg, float* __restrict__ dinv, int n) {
    int i = blockIdx.x * blockDim.x + threadIdx.x;
    if (i < n) {
        int d = deg[i];
        dinv[i] = (d > 0) ? (1.0f / sqrtf((float)d)) : 0.0f;
    }
}

// ---- 3-phase parallel exclusive scan of deg -> row_ptr[0..n] ----

__global__ __launch_bounds__(256) void scan_phase1(const int* __restrict__ deg,
                                                   int* __restrict__ blockSums, int n) {
    __shared__ int lds[256];
    int b = blockIdx.x, t = threadIdx.x;
    int base = b * SCAN_TILE + t * 4;
    int s = 0;
    if (base + 3 < n) {
        int4 v = *(const int4*)(deg + base);
        s = v.x + v.y + v.z + v.w;
    } else {
#pragma unroll
        for (int i = 0; i < 4; ++i)
            if (base + i < n) s += deg[base + i];
    }
    lds[t] = s;
    __syncthreads();
    for (int off = 128; off; off >>= 1) {
        if (t < off) lds[t] += lds[t + off];
        __syncthreads();
    }
    if (t == 0) blockSums[b] = lds[0];
}

// single wave: inclusive scan of up to 64 block sums
__global__ void scan_phase2(int* __restrict__ blockSums, int nb) {
    int t = threadIdx.x;
    int v = (t < nb) ? blockSums[t] : 0;
#pragma unroll
    for (int off = 1; off < 64; off <<= 1) {
        int u = __shfl_up(v, off);
        if (t >= off) v += u;
    }
    if (t < nb) blockSums[t] = v;  // now inclusive sums
}

__global__ __launch_bounds__(256) void scan_phase3(const int* __restrict__ deg,
                                                   const int* __restrict__ blockSumsInc,
                                                   int* __restrict__ row_ptr, int n) {
    __shared__ int lds[256];
    int b = blockIdx.x, t = threadIdx.x;
    int base = b * SCAN_TILE + t * 4;
    int e[4];
    int s = 0;
#pragma unroll
    for (int i = 0; i < 4; ++i) {
        e[i] = (base + i < n) ? deg[base + i] : 0;
        s += e[i];
    }
    lds[t] = s;
    __syncthreads();
    int v = s;
    for (int off = 1; off < 256; off <<= 1) {
        int add = (t >= off) ? lds[t - off] : 0;
        __syncthreads();
        v += add;
        lds[t] = v;
        __syncthreads();
    }
    int excl = (t == 0 ? 0 : lds[t - 1]) + (b == 0 ? 0 : blockSumsInc[b - 1]);
    if (b == 0 && t == 0) row_ptr[0] = 0;
    int run = excl;
#pragma unroll
    for (int i = 0; i < 4; ++i) {
        if (base + i < n) {
            run += e[i];
            row_ptr[base + i + 1] = run;
        }
    }
}

__global__ void scatter_kernel(const int* __restrict__ src, const int* __restrict__ dst,
                               const int* __restrict__ row_ptr, int* __restrict__ cursor,
                               const float* __restrict__ dinv,
                               int* __restrict__ col, float* __restrict__ ew, int E) {
    int e = blockIdx.x * blockDim.x + threadIdx.x;
    if (e < E) {
        int s = src[e], d = dst[e];
        int ofs = atomicAdd(&cursor[d], 1);
        int pos = row_ptr[d] + ofs;
        col[pos] = s;
        ew[pos] = dinv[s] * dinv[d];
    }
}

// ---------------- Dense GEMM (fp32 vector ALU) ----------------
template <int CIN>
__global__ __launch_bounds__(256) void gemm_kernel(
    const float* __restrict__ A, const float* __restrict__ W,
    float* __restrict__ out, int N, int COUT, int a_per_k) {
    __shared__ float xT[CIN][64];
    __shared__ float Wt[CIN * 64];

    const int k = blockIdx.y;
    const int n0 = blockIdx.x * 64;
    const int t = threadIdx.x;
    const float* Ab = A + (a_per_k ? (size_t)k * N * CIN : (size_t)0);

    {
        int nl = t & 63;
        int n = n0 + nl;
        const float* row = Ab + (size_t)n * CIN;
        for (int c0 = (t >> 6) * 4; c0 < CIN; c0 += 16) {
            float4 v = make_float4(0.f, 0.f, 0.f, 0.f);
            if (n < N) v = *(const float4*)(row + c0);
            xT[c0 + 0][nl] = v.x;
            xT[c0 + 1][nl] = v.y;
            xT[c0 + 2][nl] = v.z;
            xT[c0 + 3][nl] = v.w;
        }
    }
    {
        const float* Wk = W + (size_t)k * CIN * COUT;
        int total = CIN * COUT;
        for (int i = t * 4; i < total; i += 1024) {
            *(float4*)(&Wt[i]) = *(const float4*)(Wk + i);
        }
    }
    __syncthreads();

    const int tx = t & 15;
    const int ty = t >> 4;
    if (tx * 4 < COUT) {
        float acc[4][4] = {};
#pragma unroll 4
        for (int c = 0; c < CIN; ++c) {
            const float4 av = *(const float4*)(&xT[c][ty * 4]);
            const float4 wv = *(const float4*)(&Wt[c * COUT + tx * 4]);
            const float aa[4] = {av.x, av.y, av.z, av.w};
            const float ww[4] = {wv.x, wv.y, wv.z, wv.w};
#pragma unroll
            for (int i = 0; i < 4; ++i)
#pragma unroll
                for (int j = 0; j < 4; ++j) acc[i][j] += aa[i] * ww[j];
        }
#pragma unroll
        for (int i = 0; i < 4; ++i) {
            int n = n0 + ty * 4 + i;
            if (n < N) {
                float4 v = make_float4(acc[i][0], acc[i][1], acc[i][2], acc[i][3]);
                *(float4*)(out + ((size_t)k * N + n) * COUT + tx * 4) = v;
            }
        }
    }
}

// ---------------- Sparse aggregation: float4 gathers, 16-edge chunks ----------------
template <int F>
__global__ __launch_bounds__(256) void agg_kernel(
    const float* __restrict__ h, const int* __restrict__ row_ptr,
    const int* __restrict__ col, const float* __restrict__ ew,
    const float* __restrict__ root, const float* __restrict__ bias,
    float* __restrict__ out, int N, int do_relu) {
    constexpr int FQ = F / 4;
    int wid = (blockIdx.x * blockDim.x + threadIdx.x) >> 6;
    int lane = threadIdx.x & 63;
    int node = wid >> 1;
    int k = wid & 1;
    if (node >= N) return;
    int e0 = row_ptr[node];
    int deg = row_ptr[node + 1] - e0;
    const float* hk = h + (size_t)k * N * F;
    const int sub = lane >> 4;
    const int fq = lane & 15;
    const int fqc = (fq < FQ) ? fq : 0;

    float4 acc = make_float4(0.f, 0.f, 0.f, 0.f);
    for (int w0 = 0; w0 < deg; w0 += 64) {
        int mye = w0 + lane;
        int c = 0;
        float wt = 0.f;
        if (mye < deg) {
            c = col[e0 + mye];
            wt = ew[e0 + mye];
        }
        int nch = min(deg - w0, 64);
        for (int base = 0; base < nch; base += 16) {
            float4 v[4];
            float wj[4];
#pragma unroll
            for (int u = 0; u < 4; ++u) {
                int j = base + u * 4 + sub;
                int cj = __shfl(c, j);
                float wv = __shfl(wt, j);
                bool ok = (j < nch);
                wj[u] = ok ? wv : 0.f;
                int cs = ok ? cj : 0;
                v[u] = *(const float4*)(hk + (size_t)cs * F + fqc * 4);
            }
#pragma unroll
            for (int u = 0; u < 4; ++u) {
                acc.x += wj[u] * v[u].x;
                acc.y += wj[u] * v[u].y;
                acc.z += wj[u] * v[u].z;
                acc.w += wj[u] * v[u].w;
            }
        }
    }
#pragma unroll
    for (int m = 16; m < 64; m <<= 1) {
        acc.x += __shfl_xor(acc.x, m);
        acc.y += __shfl_xor(acc.y, m);
        acc.z += __shfl_xor(acc.z, m);
        acc.w += __shfl_xor(acc.w, m);
    }
    if (sub == 0 && fq < FQ) {
        size_t o = ((size_t)k * N + node) * F + fq * 4;
        float4 r = *(const float4*)(root + o);
        float4 b = *(const float4*)(bias + (size_t)k * F + fq * 4);
        float4 val = make_float4(acc.x + r.x + b.x, acc.y + r.y + b.y,
                                 acc.z + r.z + b.z, acc.w + r.w + b.w);
        if (do_relu) {
            val.x = fmaxf(val.x, 0.f);
            val.y = fmaxf(val.y, 0.f);
            val.z = fmaxf(val.z, 0.f);
            val.w = fmaxf(val.w, 0.f);
        }
        *(float4*)(out + o) = val;
    }
}

// h1 = relu(mean over k)
__global__ void mean_relu_kernel(const float* __restrict__ in, float* __restrict__ out,
                                 size_t cnt, size_t stride) {
    size_t i = (size_t)blockIdx.x * blockDim.x + threadIdx.x;
    if (i < cnt) out[i] = fmaxf(0.5f * (in[i] + in[i + stride]), 0.f);
}

// out = log_softmax(mean over k of g); one wave per node
__global__ __launch_bounds__(256) void lsm_kernel(const float* __restrict__ g,
                                                  float* __restrict__ out, int N) {
    int wid = (blockIdx.x * blockDim.x + threadIdx.x) >> 6;
    int lane = threadIdx.x & 63;
    if (wid >= N) return;
    float v = -INFINITY;
    if (lane < NCLS)
        v = 0.5f * (g[(size_t)wid * NCLS + lane] + g[((size_t)N + wid) * NCLS + lane]);
    float m = v;
#pragma unroll
    for (int off = 32; off; off >>= 1) m = fmaxf(m, __shfl_xor(m, off));
    float ex = (lane < NCLS) ? expf(v - m) : 0.f;
    float s = ex;
#pragma unroll
    for (int off = 32; off; off >>= 1) s += __shfl_xor(s, off);
    float r = v - m - logf(s);
    if (lane < NCLS) out[(size_t)wid * NCLS + lane] = r;
}

// ---------------- launch ----------------

static inline size_t align256(size_t x) { return (x + 255) & ~(size_t)255; }

extern "C" void kernel_launch(void* const* d_in, const int* in_sizes, int n_in,
                              void* d_out, int out_size, void* d_ws, size_t ws_size,
                              hipStream_t stream) {
    const float* x = (const float*)d_in[0];
    const int* ei = (const int*)d_in[1];
    const float* w1_init = (const float*)d_in[2];
    const float* w1 = (const float*)d_in[3];
    const float* v1 = (const float*)d_in[4];
    const float* b1 = (const float*)d_in[5];
    const float* w2_init = (const float*)d_in[6];
    const float* w2 = (const float*)d_in[7];
    const float* v2 = (const float*)d_in[8];
    const float* b2 = (const float*)d_in[9];

    const int N = in_sizes[0] / F_IN;
    const int E = in_sizes[1] / 2;
    const int* src = ei;
    const int* dst = ei + E;

    char* p = (char*)d_ws;
    auto take = [&](size_t bytes) {
        char* r = p;
        p += align256(bytes);
        return r;
    };
    int* deg = (int*)take((size_t)N * 4);
    int* cursor = (int*)take((size_t)N * 4);
    float* dinv = (float*)take((size_t)N * 4);
    int* row_ptr = (int*)take((size_t)(N + 1) * 4);
    int* blockSums = (int*)take(256 * 4);
    int* col = (int*)take((size_t)E * 4);
    float* ew = (float*)take((size_t)E * 4);
    float* bufA = (float*)take((size_t)K_STACKS * N * HID * 4);  // root
    float* bufB = (float*)take((size_t)K_STACKS * N * HID * 4);  // h
    float* bufC = (float*)take((size_t)K_STACKS * N * HID * 4);  // agg/out
    float* h1 = (float*)take((size_t)N * HID * 4);

    hipMemsetAsync(deg, 0, (size_t)N * 4, stream);
    hipMemsetAsync(cursor, 0, (size_t)N * 4, stream);

    const int TB = 256;
    const int nScanBlocks = (N + SCAN_TILE - 1) / SCAN_TILE;  // 49 for N=50000, <=64
    deg_hist_kernel<<<(E + TB - 1) / TB, TB, 0, stream>>>(dst, deg, E);
    dinv_kernel<<<(N + TB - 1) / TB, TB, 0, stream>>>(deg, dinv, N);
    scan_phase1<<<nScanBlocks, 256, 0, stream>>>(deg, blockSums, N);
    scan_phase2<<<1, 64, 0, stream>>>(blockSums, nScanBlocks);
    scan_phase3<<<nScanBlocks, 256, 0, stream>>>(deg, blockSums, row_ptr, N);
    scatter_kernel<<<(E + TB - 1) / TB, TB, 0, stream>>>(src, dst, row_ptr, cursor, dinv, col, ew, E);

    dim3 ggrid((N + 63) / 64, K_STACKS);
    const int agg_blocks = (N * K_STACKS + 3) / 4;

    // ----- layer 1: F_IN=128 -> HID=64, act=relu -----
    gemm_kernel<F_IN><<<ggrid, 256, 0, stream>>>(x, v1, bufA, N, HID, 0);       // root1
    gemm_kernel<F_IN><<<ggrid, 256, 0, stream>>>(x, w1_init, bufB, N, HID, 0);  // h (t=0)
    agg_kernel<HID><<<agg_blocks, 256, 0, stream>>>(bufB, row_ptr, col, ew, bufA, b1, bufC, N, 1);
    gemm_kernel<HID><<<ggrid, 256, 0, stream>>>(bufC, w1, bufB, N, HID, 1);     // h (t=1)
    agg_kernel<HID><<<agg_blocks, 256, 0, stream>>>(bufB, row_ptr, col, ew, bufA, b1, bufC, N, 1);
    {
        size_t cnt = (size_t)N * HID;
        mean_relu_kernel<<<(cnt + TB - 1) / TB, TB, 0, stream>>>(bufC, h1, cnt, cnt);
    }

    // ----- layer 2: HID=64 -> NCLS=40, act=identity -----
    gemm_kernel<HID><<<ggrid, 256, 0, stream>>>(h1, v2, bufA, N, NCLS, 0);        // root2
    gemm_kernel<HID><<<ggrid, 256, 0, stream>>>(h1, w2_init, bufB, N, NCLS, 0);   // g (t=0)
    agg_kernel<NCLS><<<agg_blocks, 256, 0, stream>>>(bufB, row_ptr, col, ew, bufA, b2, bufC, N, 0);
    gemm_kernel<NCLS><<<ggrid, 256, 0, stream>>>(bufC, w2, bufB, N, NCLS, 1);     // g (t=1), CIN=40
    agg_kernel<NCLS><<<agg_blocks, 256, 0, stream>>>(bufB, row_ptr, col, ew, bufA, b2, bufC, N, 0);

    lsm_kernel<<<(N + 3) / 4, 256, 0, stream>>>(bufC, (float*)d_out, N);
}

// Round 4
// 511.094 us; speedup vs baseline: 1.9932x; 1.1414x over previous
//
#include <hip/hip_runtime.h>
#include <hip/hip_bf16.h>
#include <math.h>

#define N_NODES 50000
#define F_IN 128
#define HID 64
#define NCLS 40
#define K_STACKS 2
#define SCAN_TILE 1024  // elements per scan block (256 threads x 4)

__device__ __forceinline__ unsigned int f32_to_bf16_bits(float f) {
    unsigned int u = __float_as_uint(f);
    return (u + 0x7fffu + ((u >> 16) & 1u)) >> 16;  // RNE
}

// ---------------- CSR build ----------------

__global__ void deg_hist_kernel(const int* __restrict__ dst, int* __restrict__ deg, int E) {
    int e = blockIdx.x * blockDim.x + threadIdx.x;
    if (e < E) atomicAdd(&deg[dst[e]], 1);
}

__global__ void dinv_kernel(const int* __restrict__ deg, float* __restrict__ dinv, int n) {
    int i = blockIdx.x * blockDim.x + threadIdx.x;
    if (i < n) {
        int d = deg[i];
        dinv[i] = (d > 0) ? (1.0f / sqrtf((float)d)) : 0.0f;
    }
}

// ---- 3-phase parallel exclusive scan of deg -> row_ptr[0..n]; also cursor[i]=row start ----

__global__ __launch_bounds__(256) void scan_phase1(const int* __restrict__ deg,
                                                   int* __restrict__ blockSums, int n) {
    __shared__ int lds[256];
    int b = blockIdx.x, t = threadIdx.x;
    int base = b * SCAN_TILE + t * 4;
    int s = 0;
    if (base + 3 < n) {
        int4 v = *(const int4*)(deg + base);
        s = v.x + v.y + v.z + v.w;
    } else {
#pragma unroll
        for (int i = 0; i < 4; ++i)
            if (base + i < n) s += deg[base + i];
    }
    lds[t] = s;
    __syncthreads();
    for (int off = 128; off; off >>= 1) {
        if (t < off) lds[t] += lds[t + off];
        __syncthreads();
    }
    if (t == 0) blockSums[b] = lds[0];
}

__global__ void scan_phase2(int* __restrict__ blockSums, int nb) {
    int t = threadIdx.x;
    int v = (t < nb) ? blockSums[t] : 0;
#pragma unroll
    for (int off = 1; off < 64; off <<= 1) {
        int u = __shfl_up(v, off);
        if (t >= off) v += u;
    }
    if (t < nb) blockSums[t] = v;
}

__global__ __launch_bounds__(256) void scan_phase3(const int* __restrict__ deg,
                                                   const int* __restrict__ blockSumsInc,
                                                   int* __restrict__ row_ptr,
                                                   int* __restrict__ cursor, int n) {
    __shared__ int lds[256];
    int b = blockIdx.x, t = threadIdx.x;
    int base = b * SCAN_TILE + t * 4;
    int e[4];
    int s = 0;
#pragma unroll
    for (int i = 0; i < 4; ++i) {
        e[i] = (base + i < n) ? deg[base + i] : 0;
        s += e[i];
    }
    lds[t] = s;
    __syncthreads();
    int v = s;
    for (int off = 1; off < 256; off <<= 1) {
        int add = (t >= off) ? lds[t - off] : 0;
        __syncthreads();
        v += add;
        lds[t] = v;
        __syncthreads();
    }
    int excl = (t == 0 ? 0 : lds[t - 1]) + (b == 0 ? 0 : blockSumsInc[b - 1]);
    if (b == 0 && t == 0) row_ptr[0] = 0;
    int run = excl;
#pragma unroll
    for (int i = 0; i < 4; ++i) {
        if (base + i < n) {
            cursor[base + i] = run;  // row start; scatter atomically bumps this
            run += e[i];
            row_ptr[base + i + 1] = run;
        }
    }
}

// one 8B write per edge: (col, ew bits) packed
__global__ void scatter_kernel(const int* __restrict__ src, const int* __restrict__ dst,
                               int* __restrict__ cursor, const float* __restrict__ dinv,
                               int2* __restrict__ cw, int E) {
    int e = blockIdx.x * blockDim.x + threadIdx.x;
    if (e < E) {
        int s = src[e], d = dst[e];
        int pos = atomicAdd(&cursor[d], 1);
        cw[pos] = make_int2(s, __float_as_int(dinv[s] * dinv[d]));
    }
}

// ---------------- Dense GEMM (fp32 vector ALU), optional bf16 output ----------------
template <int CIN>
__global__ __launch_bounds__(256) void gemm_kernel(
    const float* __restrict__ A, const float* __restrict__ W,
    void* __restrict__ out, int N, int COUT, int a_per_k, int out_bf16) {
    __shared__ float xT[CIN][64];
    __shared__ float Wt[CIN * 64];

    const int k = blockIdx.y;
    const int n0 = blockIdx.x * 64;
    const int t = threadIdx.x;
    const float* Ab = A + (a_per_k ? (size_t)k * N * CIN : (size_t)0);

    {
        int nl = t & 63;
        int n = n0 + nl;
        const float* row = Ab + (size_t)n * CIN;
        for (int c0 = (t >> 6) * 4; c0 < CIN; c0 += 16) {
            float4 v = make_float4(0.f, 0.f, 0.f, 0.f);
            if (n < N) v = *(const float4*)(row + c0);
            xT[c0 + 0][nl] = v.x;
            xT[c0 + 1][nl] = v.y;
            xT[c0 + 2][nl] = v.z;
            xT[c0 + 3][nl] = v.w;
        }
    }
    {
        const float* Wk = W + (size_t)k * CIN * COUT;
        int total = CIN * COUT;
        for (int i = t * 4; i < total; i += 1024) {
            *(float4*)(&Wt[i]) = *(const float4*)(Wk + i);
        }
    }
    __syncthreads();

    const int tx = t & 15;
    const int ty = t >> 4;
    if (tx * 4 < COUT) {
        float acc[4][4] = {};
#pragma unroll 4
        for (int c = 0; c < CIN; ++c) {
            const float4 av = *(const float4*)(&xT[c][ty * 4]);
            const float4 wv = *(const float4*)(&Wt[c * COUT + tx * 4]);
            const float aa[4] = {av.x, av.y, av.z, av.w};
            const float ww[4] = {wv.x, wv.y, wv.z, wv.w};
#pragma unroll
            for (int i = 0; i < 4; ++i)
#pragma unroll
                for (int j = 0; j < 4; ++j) acc[i][j] += aa[i] * ww[j];
        }
#pragma unroll
        for (int i = 0; i < 4; ++i) {
            int n = n0 + ty * 4 + i;
            if (n < N) {
                size_t o = ((size_t)k * N + n) * COUT + tx * 4;
                if (out_bf16) {
                    ushort4 s;
                    s.x = (unsigned short)f32_to_bf16_bits(acc[i][0]);
                    s.y = (unsigned short)f32_to_bf16_bits(acc[i][1]);
                    s.z = (unsigned short)f32_to_bf16_bits(acc[i][2]);
                    s.w = (unsigned short)f32_to_bf16_bits(acc[i][3]);
                    *(ushort4*)((unsigned short*)out + o) = s;
                } else {
                    *(float4*)((float*)out + o) =
                        make_float4(acc[i][0], acc[i][1], acc[i][2], acc[i][3]);
                }
            }
        }
    }
}

// ---------------- Sparse aggregation: bf16 table, uint4 gathers ----------------
// One wave per (node,k). sub = lane>>3 (8 edge slots), fq = lane&7 (8 feat octets).
// Each gather: 16 B = 8 bf16 feats; 8 lanes cover a 128 B (F=64) row contiguously.
template <int F>
__global__ __launch_bounds__(256) void agg_kernel(
    const unsigned short* __restrict__ h, const int* __restrict__ row_ptr,
    const int2* __restrict__ cw,
    const float* __restrict__ root, const float* __restrict__ bias,
    float* __restrict__ out, int N, int do_relu) {
    constexpr int FH = F / 8;  // active fq lanes: 8 (F=64), 5 (F=40)
    int wid = (blockIdx.x * blockDim.x + threadIdx.x) >> 6;
    int lane = threadIdx.x & 63;
    int node = wid >> 1;
    int k = wid & 1;
    if (node >= N) return;
    int e0 = row_ptr[node];
    int deg = row_ptr[node + 1] - e0;
    const unsigned short* hk = h + (size_t)k * N * F;
    const int sub = lane >> 3;
    const int fq = lane & 7;
    const int fqc = (fq < FH) ? fq : (FH - 1);

    float acc[8] = {};
    for (int w0 = 0; w0 < deg; w0 += 64) {
        int mye = w0 + lane;
        int c = 0;
        float wt = 0.f;
        if (mye < deg) {
            int2 p = cw[e0 + mye];
            c = p.x;
            wt = __int_as_float(p.y);
        }
        int nch = min(deg - w0, 64);
        for (int base = 0; base < nch; base += 32) {
            uint4 v[4];
            float wj[4];
#pragma unroll
            for (int u = 0; u < 4; ++u) {
                int j = base + u * 8 + sub;
                int cj = __shfl(c, j);
                float wv = __shfl(wt, j);
                bool ok = (j < nch);
                wj[u] = ok ? wv : 0.f;
                int cs = ok ? cj : 0;
                v[u] = *(const uint4*)(hk + (size_t)cs * F + fqc * 8);
            }
#pragma unroll
            for (int u = 0; u < 4; ++u) {
                const unsigned int uu[4] = {v[u].x, v[u].y, v[u].z, v[u].w};
#pragma unroll
                for (int q = 0; q < 4; ++q) {
                    float lo = __uint_as_float(uu[q] << 16);
                    float hi = __uint_as_float(uu[q] & 0xffff0000u);
                    acc[2 * q] += wj[u] * lo;
                    acc[2 * q + 1] += wj[u] * hi;
                }
            }
        }
    }
    // reduce across the 8 edge slots (lanes differing in bits 3..5)
#pragma unroll
    for (int m = 8; m < 64; m <<= 1) {
#pragma unroll
        for (int i = 0; i < 8; ++i) acc[i] += __shfl_xor(acc[i], m);
    }
    if (sub == 0 && fq < FH) {
        size_t o = ((size_t)k * N + node) * F + fq * 8;
        const float* rp = root + o;
        const float* bp = bias + (size_t)k * F + fq * 8;
        float4 r0 = *(const float4*)(rp);
        float4 r1 = *(const float4*)(rp + 4);
        float4 b0 = *(const float4*)(bp);
        float4 b1 = *(const float4*)(bp + 4);
        float res[8] = {acc[0] + r0.x + b0.x, acc[1] + r0.y + b0.y,
                        acc[2] + r0.z + b0.z, acc[3] + r0.w + b0.w,
                        acc[4] + r1.x + b1.x, acc[5] + r1.y + b1.y,
                        acc[6] + r1.z + b1.z, acc[7] + r1.w + b1.w};
        if (do_relu) {
#pragma unroll
            for (int i = 0; i < 8; ++i) res[i] = fmaxf(res[i], 0.f);
        }
        *(float4*)(out + o) = make_float4(res[0], res[1], res[2], res[3]);
        *(float4*)(out + o + 4) = make_float4(res[4], res[5], res[6], res[7]);
    }
}

// h1 = relu(mean over k)
__global__ void mean_relu_kernel(const float* __restrict__ in, float* __restrict__ out,
                                 size_t cnt, size_t stride) {
    size_t i = (size_t)blockIdx.x * blockDim.x + threadIdx.x;
    if (i < cnt) out[i] = fmaxf(0.5f * (in[i] + in[i + stride]), 0.f);
}

// out = log_softmax(mean over k of g); one wave per node
__global__ __launch_bounds__(256) void lsm_kernel(const float* __restrict__ g,
                                                  float* __restrict__ out, int N) {
    int wid = (blockIdx.x * blockDim.x + threadIdx.x) >> 6;
    int lane = threadIdx.x & 63;
    if (wid >= N) return;
    float v = -INFINITY;
    if (lane < NCLS)
        v = 0.5f * (g[(size_t)wid * NCLS + lane] + g[((size_t)N + wid) * NCLS + lane]);
    float m = v;
#pragma unroll
    for (int off = 32; off; off >>= 1) m = fmaxf(m, __shfl_xor(m, off));
    float ex = (lane < NCLS) ? expf(v - m) : 0.f;
    float s = ex;
#pragma unroll
    for (int off = 32; off; off >>= 1) s += __shfl_xor(s, off);
    float r = v - m - logf(s);
    if (lane < NCLS) out[(size_t)wid * NCLS + lane] = r;
}

// ---------------- launch ----------------

static inline size_t align256(size_t x) { return (x + 255) & ~(size_t)255; }

extern "C" void kernel_launch(void* const* d_in, const int* in_sizes, int n_in,
                              void* d_out, int out_size, void* d_ws, size_t ws_size,
                              hipStream_t stream) {
    const float* x = (const float*)d_in[0];
    const int* ei = (const int*)d_in[1];
    const float* w1_init = (const float*)d_in[2];
    const float* w1 = (const float*)d_in[3];
    const float* v1 = (const float*)d_in[4];
    const float* b1 = (const float*)d_in[5];
    const float* w2_init = (const float*)d_in[6];
    const float* w2 = (const float*)d_in[7];
    const float* v2 = (const float*)d_in[8];
    const float* b2 = (const float*)d_in[9];

    const int N = in_sizes[0] / F_IN;
    const int E = in_sizes[1] / 2;
    const int* src = ei;
    const int* dst = ei + E;

    char* p = (char*)d_ws;
    auto take = [&](size_t bytes) {
        char* r = p;
        p += align256(bytes);
        return r;
    };
    int* deg = (int*)take((size_t)N * 4);
    int* cursor = (int*)take((size_t)N * 4);
    float* dinv = (float*)take((size_t)N * 4);
    int* row_ptr = (int*)take((size_t)(N + 1) * 4);
    int* blockSums = (int*)take(256 * 4);
    int2* cw = (int2*)take((size_t)E * 8);
    float* bufA = (float*)take((size_t)K_STACKS * N * HID * 4);            // root (fp32)
    float* bufC = (float*)take((size_t)K_STACKS * N * HID * 4);            // agg out (fp32)
    unsigned short* hb = (unsigned short*)take((size_t)K_STACKS * N * HID * 2);  // h (bf16)
    float* h1 = (float*)take((size_t)N * HID * 4);

    hipMemsetAsync(deg, 0, (size_t)N * 4, stream);

    const int TB = 256;
    const int nScanBlocks = (N + SCAN_TILE - 1) / SCAN_TILE;  // 49 for N=50000, <=64
    deg_hist_kernel<<<(E + TB - 1) / TB, TB, 0, stream>>>(dst, deg, E);
    dinv_kernel<<<(N + TB - 1) / TB, TB, 0, stream>>>(deg, dinv, N);
    scan_phase1<<<nScanBlocks, 256, 0, stream>>>(deg, blockSums, N);
    scan_phase2<<<1, 64, 0, stream>>>(blockSums, nScanBlocks);
    scan_phase3<<<nScanBlocks, 256, 0, stream>>>(deg, blockSums, row_ptr, cursor, N);
    scatter_kernel<<<(E + TB - 1) / TB, TB, 0, stream>>>(src, dst, cursor, dinv, cw, E);

    dim3 ggrid((N + 63) / 64, K_STACKS);
    const int agg_blocks = (N * K_STACKS + 3) / 4;

    // ----- layer 1: F_IN=128 -> HID=64, act=relu -----
    gemm_kernel<F_IN><<<ggrid, 256, 0, stream>>>(x, v1, bufA, N, HID, 0, 0);      // root1 fp32
    gemm_kernel<F_IN><<<ggrid, 256, 0, stream>>>(x, w1_init, hb, N, HID, 0, 1);   // h t=0 bf16
    agg_kernel<HID><<<agg_blocks, 256, 0, stream>>>(hb, row_ptr, cw, bufA, b1, bufC, N, 1);
    gemm_kernel<HID><<<ggrid, 256, 0, stream>>>(bufC, w1, hb, N, HID, 1, 1);      // h t=1 bf16
    agg_kernel<HID><<<agg_blocks, 256, 0, stream>>>(hb, row_ptr, cw, bufA, b1, bufC, N, 1);
    {
        size_t cnt = (size_t)N * HID;
        mean_relu_kernel<<<(cnt + TB - 1) / TB, TB, 0, stream>>>(bufC, h1, cnt, cnt);
    }

    // ----- layer 2: HID=64 -> NCLS=40, act=identity -----
    gemm_kernel<HID><<<ggrid, 256, 0, stream>>>(h1, v2, bufA, N, NCLS, 0, 0);      // root2 fp32
    gemm_kernel<HID><<<ggrid, 256, 0, stream>>>(h1, w2_init, hb, N, NCLS, 0, 1);   // g t=0 bf16
    agg_kernel<NCLS><<<agg_blocks, 256, 0, stream>>>(hb, row_ptr, cw, bufA, b2, bufC, N, 0);
    gemm_kernel<NCLS><<<ggrid, 256, 0, stream>>>(bufC, w2, hb, N, NCLS, 1, 1);     // g t=1 bf16
    agg_kernel<NCLS><<<agg_blocks, 256, 0, stream>>>(hb, row_ptr, cw, bufA, b2, bufC, N, 0);

    lsm_kernel<<<(N + 3) / 4, 256, 0, stream>>>(bufC, (float*)d_out, N);
}

// Round 5
// 458.556 us; speedup vs baseline: 2.2216x; 1.1146x over previous
//
#include <hip/hip_runtime.h>
#include <hip/hip_bf16.h>
#include <math.h>

#define N_NODES 50000
#define F_IN 128
#define HID 64
#define NCLS 40
#define K_STACKS 2
#define SCAN_TILE 1024

typedef __attribute__((ext_vector_type(8))) short short8;
typedef __attribute__((ext_vector_type(4))) float floatx4;

__device__ __forceinline__ unsigned int f32_to_bf16_bits(float f) {
    unsigned int u = __float_as_uint(f);
    return (u + 0x7fffu + ((u >> 16) & 1u)) >> 16;  // RNE
}
__device__ __forceinline__ unsigned int pack_bf16x2(float a, float b) {
    return f32_to_bf16_bits(a) | (f32_to_bf16_bits(b) << 16);
}

// ---------------- CSR build ----------------

__global__ void deg_hist_kernel(const int* __restrict__ dst, int* __restrict__ deg, int E) {
    int e = blockIdx.x * blockDim.x + threadIdx.x;
    if (e < E) atomicAdd(&deg[dst[e]], 1);
}

__global__ void dinv_kernel(const int* __restrict__ deg, float* __restrict__ dinv, int n) {
    int i = blockIdx.x * blockDim.x + threadIdx.x;
    if (i < n) {
        int d = deg[i];
        dinv[i] = (d > 0) ? (1.0f / sqrtf((float)d)) : 0.0f;
    }
}

__global__ __launch_bounds__(256) void scan_phase1(const int* __restrict__ deg,
                                                   int* __restrict__ blockSums, int n) {
    __shared__ int lds[256];
    int b = blockIdx.x, t = threadIdx.x;
    int base = b * SCAN_TILE + t * 4;
    int s = 0;
    if (base + 3 < n) {
        int4 v = *(const int4*)(deg + base);
        s = v.x + v.y + v.z + v.w;
    } else {
#pragma unroll
        for (int i = 0; i < 4; ++i)
            if (base + i < n) s += deg[base + i];
    }
    lds[t] = s;
    __syncthreads();
    for (int off = 128; off; off >>= 1) {
        if (t < off) lds[t] += lds[t + off];
        __syncthreads();
    }
    if (t == 0) blockSums[b] = lds[0];
}

__global__ void scan_phase2(int* __restrict__ blockSums, int nb) {
    int t = threadIdx.x;
    int v = (t < nb) ? blockSums[t] : 0;
#pragma unroll
    for (int off = 1; off < 64; off <<= 1) {
        int u = __shfl_up(v, off);
        if (t >= off) v += u;
    }
    if (t < nb) blockSums[t] = v;
}

__global__ __launch_bounds__(256) void scan_phase3(const int* __restrict__ deg,
                                                   const int* __restrict__ blockSumsInc,
                                                   int* __restrict__ row_ptr,
                                                   int* __restrict__ cursor, int n) {
    __shared__ int lds[256];
    int b = blockIdx.x, t = threadIdx.x;
    int base = b * SCAN_TILE + t * 4;
    int e[4];
    int s = 0;
#pragma unroll
    for (int i = 0; i < 4; ++i) {
        e[i] = (base + i < n) ? deg[base + i] : 0;
        s += e[i];
    }
    lds[t] = s;
    __syncthreads();
    int v = s;
    for (int off = 1; off < 256; off <<= 1) {
        int add = (t >= off) ? lds[t - off] : 0;
        __syncthreads();
        v += add;
        lds[t] = v;
        __syncthreads();
    }
    int excl = (t == 0 ? 0 : lds[t - 1]) + (b == 0 ? 0 : blockSumsInc[b - 1]);
    if (b == 0 && t == 0) row_ptr[0] = 0;
    int run = excl;
#pragma unroll
    for (int i = 0; i < 4; ++i) {
        if (base + i < n) {
            cursor[base + i] = run;
            run += e[i];
            row_ptr[base + i + 1] = run;
        }
    }
}

__global__ void scatter_kernel(const int* __restrict__ src, const int* __restrict__ dst,
                               int* __restrict__ cursor, const float* __restrict__ dinv,
                               int2* __restrict__ cw, int E) {
    int e = blockIdx.x * blockDim.x + threadIdx.x;
    if (e < E) {
        int s = src[e], d = dst[e];
        int pos = atomicAdd(&cursor[d], 1);
        cw[pos] = make_int2(s, __float_as_int(dinv[s] * dinv[d]));
    }
}

// ---------------- weight pre-transpose: [k][C][F] fp32 -> [k][F][CP] bf16, zero-pad c>=C ----
__global__ void wt_transpose_kernel(const float* __restrict__ in, unsigned short* __restrict__ out,
                                    int KK, int C, int F, int CP) {
    int idx = blockIdx.x * blockDim.x + threadIdx.x;
    int total = KK * F * CP;
    if (idx >= total) return;
    int k = idx / (F * CP);
    int r = idx - k * F * CP;
    int f = r / CP;
    int c = r - f * CP;
    out[idx] = (c < C) ? (unsigned short)f32_to_bf16_bits(in[((size_t)k * C + c) * F + f]) : 0;
}

// ---------------- MFMA GEMM: out[k][n][f] = A[(k)][n][0:CREAL] . W[k][:, f] ----------------
// A fp32 (row stride CREAL, bf16-converted during staging), Bt bf16 pre-transposed [k][f][CINP]
// (zero-padded to CINP). Block: 256 thr = 4 waves; 64 nodes x COUT. LDS XOR-swizzled chunks.
// Frag layouts (guide §3, m89/m118-verified): A/B [idx=lane&15][k=quad*8+j]; D col=lane&15,
// row=quad*4+reg.
template <int CINP>
__global__ __launch_bounds__(256) void gemm_mfma(
    const float* __restrict__ A, const unsigned short* __restrict__ Bt,
    void* __restrict__ out, int N, int COUT, int CREAL, int a_per_k, int out_bf16) {
    constexpr int CP8 = CINP / 8;       // 16B chunks per row
    constexpr int MS = CP8 - 1;         // swizzle mask
    constexpr int SH = (CP8 == 16) ? 4 : 3;
    __shared__ __align__(16) unsigned short At[64 * CINP];
    __shared__ __align__(16) unsigned short Bs[64 * CINP];

    const int k = blockIdx.y;
    const int n0 = blockIdx.x * 64;
    const int t = threadIdx.x;
    const float* Ab = A + (a_per_k ? (size_t)k * N * CREAL : (size_t)0);
    const unsigned short* Bk = Bt + (size_t)k * COUT * CINP;

    // stage A: fp32 -> bf16, swizzled chunk writes
    for (int i = t; i < 64 * CP8; i += 256) {
        int n = i >> SH;
        int c = i & MS;
        uint4 w = make_uint4(0u, 0u, 0u, 0u);
        int gn = n0 + n;
        if (gn < N && c * 8 < CREAL) {
            const float* srcp = Ab + (size_t)gn * CREAL + c * 8;
            float4 f0 = *(const float4*)(srcp);
            float4 f1 = *(const float4*)(srcp + 4);
            w.x = pack_bf16x2(f0.x, f0.y);
            w.y = pack_bf16x2(f0.z, f0.w);
            w.z = pack_bf16x2(f1.x, f1.y);
            w.w = pack_bf16x2(f1.z, f1.w);
        }
        *(uint4*)(At + n * CINP + ((c ^ (n & MS)) << 3)) = w;
    }
    // stage B: already bf16 + padded; swizzled copy
    for (int i = t; i < COUT * CP8; i += 256) {
        int f = i >> SH;
        int c = i & MS;
        uint4 w = *(const uint4*)(Bk + f * CINP + c * 8);
        *(uint4*)(Bs + f * CINP + ((c ^ (f & MS)) << 3)) = w;
    }
    __syncthreads();

    const int lane = t & 63;
    const int wv = t >> 6;
    const int quad = lane >> 4;
    const int li = lane & 15;
    const int m0 = wv * 16;

    floatx4 acc[4] = {{0.f, 0.f, 0.f, 0.f}, {0.f, 0.f, 0.f, 0.f},
                      {0.f, 0.f, 0.f, 0.f}, {0.f, 0.f, 0.f, 0.f}};
    const int am = (m0 + li) & MS;
#pragma unroll
    for (int kc = 0; kc < CINP / 32; ++kc) {
        int cc = kc * 4 + quad;
        short8 a = *(const short8*)(At + (m0 + li) * CINP + ((cc ^ am) << 3));
#pragma unroll
        for (int nt = 0; nt < 4; ++nt) {
            if (nt * 16 < COUT) {
                int f = nt * 16 + li;
                short8 b = *(const short8*)(Bs + f * CINP + ((cc ^ (f & MS)) << 3));
                acc[nt] = __builtin_amdgcn_mfma_f32_16x16x32_bf16(a, b, acc[nt], 0, 0, 0);
            }
        }
    }

#pragma unroll
    for (int nt = 0; nt < 4; ++nt) {
        if (nt * 16 >= COUT) continue;
        int f = nt * 16 + li;
        if (f >= COUT) continue;
#pragma unroll
        for (int r = 0; r < 4; ++r) {
            int node = n0 + m0 + quad * 4 + r;
            if (node < N) {
                size_t o = ((size_t)k * N + node) * COUT + f;
                if (out_bf16)
                    ((unsigned short*)out)[o] = (unsigned short)f32_to_bf16_bits(acc[nt][r]);
                else
                    ((float*)out)[o] = acc[nt][r];
            }
        }
    }
}

// ---------------- Sparse aggregation: bf16 table, uint4 gathers (round-4 proven) ----------
template <int F>
__global__ __launch_bounds__(256) void agg_kernel(
    const unsigned short* __restrict__ h, const int* __restrict__ row_ptr,
    const int2* __restrict__ cw,
    const float* __restrict__ root, const float* __restrict__ bias,
    float* __restrict__ out, int N, int do_relu) {
    constexpr int FH = F / 8;
    int wid = (blockIdx.x * blockDim.x + threadIdx.x) >> 6;
    int lane = threadIdx.x & 63;
    int node = wid >> 1;
    int k = wid & 1;
    if (node >= N) return;
    int e0 = row_ptr[node];
    int deg = row_ptr[node + 1] - e0;
    const unsigned short* hk = h + (size_t)k * N * F;
    const int sub = lane >> 3;
    const int fq = lane & 7;
    const int fqc = (fq < FH) ? fq : (FH - 1);

    float acc[8] = {};
    for (int w0 = 0; w0 < deg; w0 += 64) {
        int mye = w0 + lane;
        int c = 0;
        float wt = 0.f;
        if (mye < deg) {
            int2 p = cw[e0 + mye];
            c = p.x;
            wt = __int_as_float(p.y);
        }
        int nch = min(deg - w0, 64);
        for (int base = 0; base < nch; base += 32) {
            uint4 v[4];
            float wj[4];
#pragma unroll
            for (int u = 0; u < 4; ++u) {
                int j = base + u * 8 + sub;
                int cj = __shfl(c, j);
                float wv2 = __shfl(wt, j);
                bool ok = (j < nch);
                wj[u] = ok ? wv2 : 0.f;
                int cs = ok ? cj : 0;
                v[u] = *(const uint4*)(hk + (size_t)cs * F + fqc * 8);
            }
#pragma unroll
            for (int u = 0; u < 4; ++u) {
                const unsigned int uu[4] = {v[u].x, v[u].y, v[u].z, v[u].w};
#pragma unroll
                for (int q = 0; q < 4; ++q) {
                    float lo = __uint_as_float(uu[q] << 16);
                    float hi = __uint_as_float(uu[q] & 0xffff0000u);
                    acc[2 * q] += wj[u] * lo;
                    acc[2 * q + 1] += wj[u] * hi;
                }
            }
        }
    }
#pragma unroll
    for (int m = 8; m < 64; m <<= 1) {
#pragma unroll
        for (int i = 0; i < 8; ++i) acc[i] += __shfl_xor(acc[i], m);
    }
    if (sub == 0 && fq < FH) {
        size_t o = ((size_t)k * N + node) * F + fq * 8;
        const float* rp = root + o;
        const float* bp = bias + (size_t)k * F + fq * 8;
        float4 r0 = *(const float4*)(rp);
        float4 r1 = *(const float4*)(rp + 4);
        float4 b0 = *(const float4*)(bp);
        float4 b1 = *(const float4*)(bp + 4);
        float res[8] = {acc[0] + r0.x + b0.x, acc[1] + r0.y + b0.y,
                        acc[2] + r0.z + b0.z, acc[3] + r0.w + b0.w,
                        acc[4] + r1.x + b1.x, acc[5] + r1.y + b1.y,
                        acc[6] + r1.z + b1.z, acc[7] + r1.w + b1.w};
        if (do_relu) {
#pragma unroll
            for (int i = 0; i < 8; ++i) res[i] = fmaxf(res[i], 0.f);
        }
        *(float4*)(out + o) = make_float4(res[0], res[1], res[2], res[3]);
        *(float4*)(out + o + 4) = make_float4(res[4], res[5], res[6], res[7]);
    }
}

// h1 = relu(mean over k)
__global__ void mean_relu_kernel(const float* __restrict__ in, float* __restrict__ out,
                                 size_t cnt, size_t stride) {
    size_t i = (size_t)blockIdx.x * blockDim.x + threadIdx.x;
    if (i < cnt) out[i] = fmaxf(0.5f * (in[i] + in[i + stride]), 0.f);
}

// out = log_softmax(mean over k of g); one wave per node
__global__ __launch_bounds__(256) void lsm_kernel(const float* __restrict__ g,
                                                  float* __restrict__ out, int N) {
    int wid = (blockIdx.x * blockDim.x + threadIdx.x) >> 6;
    int lane = threadIdx.x & 63;
    if (wid >= N) return;
    float v = -INFINITY;
    if (lane < NCLS)
        v = 0.5f * (g[(size_t)wid * NCLS + lane] + g[((size_t)N + wid) * NCLS + lane]);
    float m = v;
#pragma unroll
    for (int off = 32; off; off >>= 1) m = fmaxf(m, __shfl_xor(m, off));
    float ex = (lane < NCLS) ? expf(v - m) : 0.f;
    float s = ex;
#pragma unroll
    for (int off = 32; off; off >>= 1) s += __shfl_xor(s, off);
    float r = v - m - logf(s);
    if (lane < NCLS) out[(size_t)wid * NCLS + lane] = r;
}

// ---------------- launch ----------------

static inline size_t align256(size_t x) { return (x + 255) & ~(size_t)255; }

extern "C" void kernel_launch(void* const* d_in, const int* in_sizes, int n_in,
                              void* d_out, int out_size, void* d_ws, size_t ws_size,
                              hipStream_t stream) {
    const float* x = (const float*)d_in[0];
    const int* ei = (const int*)d_in[1];
    const float* w1_init = (const float*)d_in[2];
    const float* w1 = (const float*)d_in[3];
    const float* v1 = (const float*)d_in[4];
    const float* b1 = (const float*)d_in[5];
    const float* w2_init = (const float*)d_in[6];
    const float* w2 = (const float*)d_in[7];
    const float* v2 = (const float*)d_in[8];
    const float* b2 = (const float*)d_in[9];

    const int N = in_sizes[0] / F_IN;
    const int E = in_sizes[1] / 2;
    const int* src = ei;
    const int* dst = ei + E;

    char* p = (char*)d_ws;
    auto take = [&](size_t bytes) {
        char* r = p;
        p += align256(bytes);
        return r;
    };
    int* deg = (int*)take((size_t)N * 4);
    int* cursor = (int*)take((size_t)N * 4);
    float* dinv = (float*)take((size_t)N * 4);
    int* row_ptr = (int*)take((size_t)(N + 1) * 4);
    int* blockSums = (int*)take(256 * 4);
    int2* cw = (int2*)take((size_t)E * 8);
    // bf16 transposed weights: [k][F][CP]
    unsigned short* v1t = (unsigned short*)take((size_t)2 * 64 * 128 * 2);
    unsigned short* w1it = (unsigned short*)take((size_t)2 * 64 * 128 * 2);
    unsigned short* w1t = (unsigned short*)take((size_t)2 * 64 * 64 * 2);
    unsigned short* v2t = (unsigned short*)take((size_t)2 * 40 * 64 * 2);
    unsigned short* w2it = (unsigned short*)take((size_t)2 * 40 * 64 * 2);
    unsigned short* w2t = (unsigned short*)take((size_t)2 * 40 * 64 * 2);
    float* bufA = (float*)take((size_t)K_STACKS * N * HID * 4);            // root fp32
    float* bufC = (float*)take((size_t)K_STACKS * N * HID * 4);            // agg out fp32
    unsigned short* hb = (unsigned short*)take((size_t)K_STACKS * N * HID * 2);  // gemm bf16 out
    float* h1 = (float*)take((size_t)N * HID * 4);

    hipMemsetAsync(deg, 0, (size_t)N * 4, stream);

    const int TB = 256;
    const int nScanBlocks = (N + SCAN_TILE - 1) / SCAN_TILE;
    deg_hist_kernel<<<(E + TB - 1) / TB, TB, 0, stream>>>(dst, deg, E);
    dinv_kernel<<<(N + TB - 1) / TB, TB, 0, stream>>>(deg, dinv, N);
    scan_phase1<<<nScanBlocks, 256, 0, stream>>>(deg, blockSums, N);
    scan_phase2<<<1, 64, 0, stream>>>(blockSums, nScanBlocks);
    scan_phase3<<<nScanBlocks, 256, 0, stream>>>(deg, blockSums, row_ptr, cursor, N);
    scatter_kernel<<<(E + TB - 1) / TB, TB, 0, stream>>>(src, dst, cursor, dinv, cw, E);

    // weight prep (tiny)
    auto wt = [&](const float* in, unsigned short* out, int C, int F, int CP) {
        int total = 2 * F * CP;
        wt_transpose_kernel<<<(total + TB - 1) / TB, TB, 0, stream>>>(in, out, 2, C, F, CP);
    };
    wt(v1, v1t, 128, 64, 128);
    wt(w1_init, w1it, 128, 64, 128);
    wt(w1, w1t, 64, 64, 64);
    wt(v2, v2t, 64, 40, 64);
    wt(w2_init, w2it, 64, 40, 64);
    wt(w2, w2t, 40, 40, 64);

    dim3 ggrid((N + 63) / 64, K_STACKS);
    const int agg_blocks = (N * K_STACKS + 3) / 4;

    // ----- layer 1: F_IN=128 -> HID=64, act=relu -----
    gemm_mfma<128><<<ggrid, 256, 0, stream>>>(x, v1t, bufA, N, HID, 128, 0, 0);   // root1 fp32
    gemm_mfma<128><<<ggrid, 256, 0, stream>>>(x, w1it, hb, N, HID, 128, 0, 1);    // h t=0 bf16
    agg_kernel<HID><<<agg_blocks, 256, 0, stream>>>(hb, row_ptr, cw, bufA, b1, bufC, N, 1);
    gemm_mfma<64><<<ggrid, 256, 0, stream>>>(bufC, w1t, hb, N, HID, 64, 1, 1);    // h t=1 bf16
    agg_kernel<HID><<<agg_blocks, 256, 0, stream>>>(hb, row_ptr, cw, bufA, b1, bufC, N, 1);
    {
        size_t cnt = (size_t)N * HID;
        mean_relu_kernel<<<(cnt + TB - 1) / TB, TB, 0, stream>>>(bufC, h1, cnt, cnt);
    }

    // ----- layer 2: HID=64 -> NCLS=40, act=identity -----
    gemm_mfma<64><<<ggrid, 256, 0, stream>>>(h1, v2t, bufA, N, NCLS, 64, 0, 0);   // root2 fp32
    gemm_mfma<64><<<ggrid, 256, 0, stream>>>(h1, w2it, hb, N, NCLS, 64, 0, 1);    // g t=0 bf16
    agg_kernel<NCLS><<<agg_blocks, 256, 0, stream>>>(hb, row_ptr, cw, bufA, b2, bufC, N, 0);
    gemm_mfma<64><<<ggrid, 256, 0, stream>>>(bufC, w2t, hb, N, NCLS, 40, 1, 1);   // g t=1 bf16
    agg_kernel<NCLS><<<agg_blocks, 256, 0, stream>>>(hb, row_ptr, cw, bufA, b2, bufC, N, 0);

    lsm_kernel<<<(N + 3) / 4, 256, 0, stream>>>(bufC, (float*)d_out, N);
}